// Round 2
// baseline (556.465 us; speedup 1.0000x reference)
//
#include <hip/hip_runtime.h>

#define N_NODES 100000
#define N_EDGES 1600000
#define D_IN    128
#define D_OUT   64

// ---------------------------------------------------------------------------
// Kernel A: support = X @ W   (fp32)
// block = 256 threads = 4 rows x 64 cols; W staged in LDS [k][col].
// Writes fp32 support into d_out[N*64 : 2*N*64] (tuple element 1).
// ---------------------------------------------------------------------------
__global__ __launch_bounds__(256) void gcn_gemm(
    const float* __restrict__ x,        // [N, 128]
    const float* __restrict__ w,        // [128, 64]
    float* __restrict__ support)        // [N, 64] (= d_out + N*64)
{
    __shared__ float wl[D_IN * D_OUT];  // 32 KB, layout [k][col]
    __shared__ float xl[4][D_IN];       // 2 KB

    const int tid = threadIdx.x;
    for (int i = tid; i < D_IN * D_OUT; i += 256)
        wl[i] = w[i];

    const int r   = tid >> 6;   // row within block (0..3) == wave id
    const int col = tid & 63;
    const long row = (long)blockIdx.x * 4 + r;   // grid is exact: N%4==0

    // each wave loads its own x row: 128 floats / 64 lanes = float2 each
    const float2 xv = *(const float2*)&x[row * D_IN + col * 2];
    xl[r][col * 2]     = xv.x;
    xl[r][col * 2 + 1] = xv.y;
    __syncthreads();

    float acc = 0.f;
#pragma unroll
    for (int k = 0; k < D_IN; ++k)
        acc = fmaf(xl[r][k], wl[k * D_OUT + col], acc);

    support[row * D_OUT + col] = acc;
}

// ---------------------------------------------------------------------------
// Kernel B: for each edge e: out[rows[e]][:] += vals[e] * support[cols[e]][:]
// one wave per edge, lane = output column, fp32 atomics into d_out first half
// (pre-zeroed by memset). support is read from d_out second half (disjoint).
// ---------------------------------------------------------------------------
__global__ __launch_bounds__(256) void gcn_scatter(
    const int* __restrict__ rows,
    const int* __restrict__ cols,
    const float* __restrict__ vals,
    const float* __restrict__ support,  // [N, 64] fp32
    float* __restrict__ accum)          // [N, 64] fp32 (= d_out first half)
{
    const int lane = threadIdx.x & 63;
    const int e    = blockIdx.x * 4 + (threadIdx.x >> 6);  // grid exact: E%4==0

    const int   r = rows[e];
    const int   c = cols[e];
    const float v = vals[e];
    const float s = support[(long)c * D_OUT + lane];
    atomicAdd(&accum[(long)r * D_OUT + lane], v * s);
}

// ---------------------------------------------------------------------------
// Kernel C: PReLU in place on d_out first half
// ---------------------------------------------------------------------------
__global__ __launch_bounds__(256) void gcn_prelu(
    float* __restrict__ out,
    const float* __restrict__ prelu_a)
{
    const float a = prelu_a[0];
    const int i = blockIdx.x * 256 + threadIdx.x;   // grid exact
    const float v = out[i];
    out[i] = v > 0.f ? v : a * v;
}

// ---------------------------------------------------------------------------
extern "C" void kernel_launch(void* const* d_in, const int* in_sizes, int n_in,
                              void* d_out, int out_size, void* d_ws, size_t ws_size,
                              hipStream_t stream) {
    const float* x    = (const float*)d_in[0];
    const int*   rows = (const int*)d_in[1];
    const int*   cols = (const int*)d_in[2];
    const float* vals = (const float*)d_in[3];
    const float* w    = (const float*)d_in[4];
    const float* pa   = (const float*)d_in[5];

    float* out     = (float*)d_out;                       // [N*64] PReLU output
    float* support = out + (size_t)N_NODES * D_OUT;       // [N*64] support (tuple elem 1)

    // accumulator must be zero every call (d_out is re-poisoned to 0xAA)
    hipMemsetAsync(out, 0, (size_t)N_NODES * D_OUT * sizeof(float), stream);

    gcn_gemm   <<<N_NODES / 4, 256, 0, stream>>>(x, w, support);
    gcn_scatter<<<N_EDGES / 4, 256, 0, stream>>>(rows, cols, vals, support, out);
    gcn_prelu  <<<N_NODES * D_OUT / 256, 256, 0, stream>>>(out, pa);
}